// Round 1
// baseline (229.958 us; speedup 1.0000x reference)
//
#include <hip/hip_runtime.h>
#include <cstdint>
#include <cstddef>

typedef unsigned short u16;
typedef unsigned int u32;
typedef __bf16 bf16x8 __attribute__((ext_vector_type(8)));
typedef float f32x4 __attribute__((ext_vector_type(4)));

// f32 -> bf16 round-to-nearest-even (finite inputs only)
__device__ __forceinline__ u16 f2bf(float f) {
    u32 u = __float_as_uint(f);
    u += 0x7fffu + ((u >> 16) & 1u);
    return (u16)(u >> 16);
}

// async global->LDS, 16B per lane. LDS ptr must be wave-uniform; HW adds lane*16.
__device__ __forceinline__ void gl16(const void* g, void* l) {
    __builtin_amdgcn_global_load_lds(
        (const __attribute__((address_space(1))) unsigned int*)g,
        (__attribute__((address_space(3))) unsigned int*)l, 16, 0, 0);
}

// ---------------------------------------------------------------- conversions
__global__ __launch_bounds__(256) void cvt_x_k(const float* __restrict__ x,
                                               u16* __restrict__ o) {
    int i = blockIdx.x * 256 + threadIdx.x;   // 2048*256 threads * 8 elems = 4194304
    const float4* xv = (const float4*)x;
    float4 a = xv[2 * i], b = xv[2 * i + 1];
    ushort4 r0, r1;
    r0.x = f2bf(a.x); r0.y = f2bf(a.y); r0.z = f2bf(a.z); r0.w = f2bf(a.w);
    r1.x = f2bf(b.x); r1.y = f2bf(b.y); r1.z = f2bf(b.z); r1.w = f2bf(b.w);
    ((ushort4*)o)[2 * i] = r0;
    ((ushort4*)o)[2 * i + 1] = r1;
}

// W [1024][1024] f32 row-major (k,n) -> out [1024][1024] bf16 (n,k)  (i.e. W^T)
__global__ __launch_bounds__(256) void cvt_wT_k(const float* __restrict__ W,
                                                u16* __restrict__ o) {
    __shared__ float tile[64][65];
    const int bx = blockIdx.x, by = blockIdx.y;
    const int t = threadIdx.x, tn = t & 63, tr = t >> 6;
#pragma unroll
    for (int r = 0; r < 16; ++r) {
        int kk = r * 4 + tr;
        tile[kk][tn] = W[(size_t)(by * 64 + kk) * 1024 + bx * 64 + tn];
    }
    __syncthreads();
#pragma unroll
    for (int r = 0; r < 16; ++r) {
        int nn = r * 4 + tr;
        o[(size_t)(bx * 64 + nn) * 1024 + by * 64 + tn] = f2bf(tile[tn][nn]);
    }
}

// ---------------------------------------------------------------- GEMM 128x128
// A [M][1024] bf16 row-major, Bt [N][1024] bf16 (= B^T), K=1024.
// MODE 0: fused QKV epilogue -> q,k as [BH][2048][64], v transposed [BH][64][2048]
// MODE 1: f32 out [M][1024] + bias
template <int MODE>
__global__ __launch_bounds__(256) void gemm_k(
    const u16* __restrict__ A, const u16* __restrict__ Bt,
    const float* __restrict__ bias0, const float* __restrict__ bias1,
    const float* __restrict__ bias2,
    u16* __restrict__ oq, u16* __restrict__ ok_, u16* __restrict__ ov,
    float* __restrict__ oc) {
    __shared__ __align__(16) u16 As[128 * 32];
    __shared__ __align__(16) u16 Bs[128 * 32];
    const int t = threadIdx.x, w = t >> 6, lane = t & 63;
    const int lr = lane & 15, lg = lane >> 4;
    const int brow = blockIdx.x * 128, bcol = blockIdx.y * 128;
    const int wr = w >> 1, wc = w & 1;
    const char* Ab = (const char*)A + (size_t)brow * 2048;
    const char* Bb = (const char*)Bt + (size_t)bcol * 2048;
    char* AsB = (char*)As;
    char* BsB = (char*)Bs;
    const int lrow = lane >> 2, lcol = (lane & 3) << 4;
    f32x4 acc[4][4];
#pragma unroll
    for (int m = 0; m < 4; ++m)
#pragma unroll
        for (int n = 0; n < 4; ++n) acc[m][n] = (f32x4){0.f, 0.f, 0.f, 0.f};

    for (int k0 = 0; k0 < 1024; k0 += 32) {
#pragma unroll
        for (int i = 0; i < 2; ++i) {
            int r0 = w * 32 + i * 16;   // 16 rows x 64B = 1KB per instruction
            gl16(Ab + (size_t)(r0 + lrow) * 2048 + k0 * 2 + lcol, AsB + r0 * 64);
            gl16(Bb + (size_t)(r0 + lrow) * 2048 + k0 * 2 + lcol, BsB + r0 * 64);
        }
        __syncthreads();
        bf16x8 af[4], bfr[4];
#pragma unroll
        for (int m = 0; m < 4; ++m)
            af[m] = *(const bf16x8*)(AsB + (wr * 64 + m * 16 + lr) * 64 + lg * 16);
#pragma unroll
        for (int n = 0; n < 4; ++n)
            bfr[n] = *(const bf16x8*)(BsB + (wc * 64 + n * 16 + lr) * 64 + lg * 16);
#pragma unroll
        for (int m = 0; m < 4; ++m)
#pragma unroll
            for (int n = 0; n < 4; ++n)
                acc[m][n] = __builtin_amdgcn_mfma_f32_16x16x32_bf16(af[m], bfr[n],
                                                                    acc[m][n], 0, 0, 0);
        __syncthreads();
    }

#pragma unroll
    for (int n = 0; n < 4; ++n) {
        const int col = bcol + wc * 64 + n * 16 + lr;
        if (MODE == 0) {
#pragma unroll
            for (int m = 0; m < 4; ++m)
#pragma unroll
                for (int r = 0; r < 4; ++r) {
                    int row = brow + wr * 64 + m * 16 + 4 * lg + r;
                    int b = row >> 11, l = row & 2047;
                    float val = acc[m][n][r];
                    if (col < 1024) {
                        int hh = col >> 6, d = col & 63;
                        oq[(((size_t)b * 16 + hh) * 2048 + l) * 64 + d] =
                            f2bf(val + bias0[col]);
                    } else if (col < 2048) {
                        int c = col - 1024, hh = c >> 6, d = c & 63;
                        ok_[(((size_t)b * 16 + hh) * 2048 + l) * 64 + d] =
                            f2bf(val + bias1[c]);
                    } else {
                        int c = col - 2048, hh = c >> 6, d = c & 63;
                        ov[(((size_t)b * 16 + hh) * 64 + d) * 2048 + l] =
                            f2bf(val + bias2[c]);
                    }
                }
        } else {
            const float bb = bias0[col];
#pragma unroll
            for (int m = 0; m < 4; ++m)
#pragma unroll
                for (int r = 0; r < 4; ++r) {
                    int row = brow + wr * 64 + m * 16 + 4 * lg + r;
                    oc[(size_t)row * 1024 + col] = acc[m][n][r] + bb;
                }
        }
    }
}

// ---------------------------------------------------------------- attention
// q,k: [BH][2048][64] bf16; vt: [BH][64][2048] bf16 (V^T per head)
// ao:  [B*2048][1024] bf16
__global__ __launch_bounds__(256) void attn_k(const u16* __restrict__ qg_,
                                              const u16* __restrict__ kg_,
                                              const u16* __restrict__ vg_,
                                              u16* __restrict__ ao) {
    __shared__ __align__(16) u16 Qt[64 * 64];
    __shared__ __align__(16) u16 Kt[64 * 64];
    __shared__ __align__(16) u16 Vt[64 * 64];   // V^T tile: [d][key]
    __shared__ __align__(16) u16 Pb[4][16 * 72]; // per-wave P, padded rows (144B)
    const int t = threadIdx.x, w = t >> 6, lane = t & 63;
    const int lr = lane & 15, lg = lane >> 4;
    const int q0 = blockIdx.x * 64, bh = blockIdx.y, h = bh & 15, b = bh >> 4;
    const float slope = exp2f(-0.5f * (float)(h + 1));
    char* QtB = (char*)Qt; char* KtB = (char*)Kt; char* VtB = (char*)Vt;

    // stage Q tile (contiguous 8KB), XOR-swizzled source, linear LDS dest
    const char* qsrc = (const char*)(qg_ + ((size_t)bh * 2048 + q0) * 64);
#pragma unroll
    for (int i = 0; i < 2; ++i) {
        int U = (w * 2 + i) * 64 + lane, rr = U >> 3, u = U & 7;
        gl16(qsrc + rr * 128 + ((u ^ (rr & 7)) << 4), QtB + (w * 2 + i) * 1024);
    }
    __syncthreads();
    bf16x8 qa[2];
#pragma unroll
    for (int kk = 0; kk < 2; ++kk)
        qa[kk] = *(const bf16x8*)(QtB + (w * 16 + lr) * 128 +
                                  (((kk * 4 + lg) ^ (lr & 7)) << 4));

    float mrun[4], lrun[4];
    f32x4 oacc[4];
#pragma unroll
    for (int r = 0; r < 4; ++r) { mrun[r] = -1e30f; lrun[r] = 0.f; }
#pragma unroll
    for (int n = 0; n < 4; ++n) oacc[n] = (f32x4){0.f, 0.f, 0.f, 0.f};

    const char* khead = (const char*)(kg_ + (size_t)bh * 2048 * 64);
    const char* vhead = (const char*)(vg_ + (size_t)bh * 64 * 2048);
    const int qrow0 = q0 + w * 16 + 4 * lg;

    for (int j0 = 0; j0 < 2048; j0 += 64) {
        const char* ks = khead + (size_t)j0 * 128;
        const char* vs = vhead + (size_t)j0 * 2;
#pragma unroll
        for (int i = 0; i < 2; ++i) {
            int U = (w * 2 + i) * 64 + lane, rr = U >> 3, u = U & 7;
            gl16(ks + rr * 128 + ((u ^ (rr & 7)) << 4), KtB + (w * 2 + i) * 1024);
            gl16(vs + (size_t)rr * 4096 + ((u ^ (rr & 7)) << 4),
                 VtB + (w * 2 + i) * 1024);
        }
        __syncthreads();

        // S = Q K^T  (wave strip: 16 q-rows x 64 keys)
        f32x4 sa[4];
#pragma unroll
        for (int n = 0; n < 4; ++n) sa[n] = (f32x4){0.f, 0.f, 0.f, 0.f};
#pragma unroll
        for (int kk = 0; kk < 2; ++kk)
#pragma unroll
            for (int n = 0; n < 4; ++n) {
                bf16x8 kf = *(const bf16x8*)(KtB + (n * 16 + lr) * 128 +
                                             (((kk * 4 + lg) ^ (lr & 7)) << 4));
                sa[n] = __builtin_amdgcn_mfma_f32_16x16x32_bf16(qa[kk], kf, sa[n],
                                                                0, 0, 0);
            }

        // scale + ALiBi, online softmax (rows 4*lg+r; reduce over 16-lane groups)
        float p[4][4], mx[4];
#pragma unroll
        for (int r = 0; r < 4; ++r) mx[r] = -1e30f;
#pragma unroll
        for (int n = 0; n < 4; ++n) {
            const float jb = (float)(j0 + n * 16 + lr);
#pragma unroll
            for (int r = 0; r < 4; ++r) {
                float s = sa[n][r] * 0.125f + slope * (jb - (float)(qrow0 + r));
                p[n][r] = s;
                mx[r] = fmaxf(mx[r], s);
            }
        }
#pragma unroll
        for (int m = 1; m < 16; m <<= 1)
#pragma unroll
            for (int r = 0; r < 4; ++r) mx[r] = fmaxf(mx[r], __shfl_xor(mx[r], m));
        float corr[4], rs[4];
#pragma unroll
        for (int r = 0; r < 4; ++r) {
            float mn = fmaxf(mrun[r], mx[r]);
            corr[r] = __expf(mrun[r] - mn);
            mrun[r] = mn;
            rs[r] = 0.f;
        }
#pragma unroll
        for (int n = 0; n < 4; ++n)
#pragma unroll
            for (int r = 0; r < 4; ++r) {
                float e = __expf(p[n][r] - mrun[r]);
                p[n][r] = e;
                rs[r] += e;
            }
#pragma unroll
        for (int m = 1; m < 16; m <<= 1)
#pragma unroll
            for (int r = 0; r < 4; ++r) rs[r] += __shfl_xor(rs[r], m);
#pragma unroll
        for (int r = 0; r < 4; ++r) lrun[r] = lrun[r] * corr[r] + rs[r];
#pragma unroll
        for (int n = 0; n < 4; ++n)
#pragma unroll
            for (int r = 0; r < 4; ++r) oacc[n][r] *= corr[r];

        // P (C-layout) -> per-wave LDS -> A-layout fragments
        u16* pw = Pb[w];
#pragma unroll
        for (int n = 0; n < 4; ++n)
#pragma unroll
            for (int r = 0; r < 4; ++r)
                pw[(4 * lg + r) * 72 + n * 16 + lr] = f2bf(p[n][r]);
        asm volatile("s_waitcnt lgkmcnt(0)" ::: "memory");
        __builtin_amdgcn_sched_barrier(0);
        bf16x8 pa[2];
#pragma unroll
        for (int kk = 0; kk < 2; ++kk)
            pa[kk] = *(const bf16x8*)((const char*)pw + lr * 144 +
                                      (kk * 4 + lg) * 16);
#pragma unroll
        for (int kk = 0; kk < 2; ++kk)
#pragma unroll
            for (int n = 0; n < 4; ++n) {
                bf16x8 vf = *(const bf16x8*)(VtB + (n * 16 + lr) * 128 +
                                             (((kk * 4 + lg) ^ (lr & 7)) << 4));
                oacc[n] = __builtin_amdgcn_mfma_f32_16x16x32_bf16(pa[kk], vf,
                                                                  oacc[n], 0, 0, 0);
            }
        __syncthreads();
    }

#pragma unroll
    for (int r = 0; r < 4; ++r) lrun[r] = 1.0f / lrun[r];
#pragma unroll
    for (int n = 0; n < 4; ++n)
#pragma unroll
        for (int r = 0; r < 4; ++r) {
            int qrow = qrow0 + r, d = n * 16 + lr;
            ao[((size_t)b * 2048 + qrow) * 1024 + h * 64 + d] =
                f2bf(oacc[n][r] * lrun[r]);
        }
}

// ---------------------------------------------------------------- launch
extern "C" void kernel_launch(void* const* d_in, const int* in_sizes, int n_in,
                              void* d_out, int out_size, void* d_ws, size_t ws_size,
                              hipStream_t stream) {
    const float* x  = (const float*)d_in[0];
    const float* Wq = (const float*)d_in[1];
    const float* bq = (const float*)d_in[2];
    const float* Wk = (const float*)d_in[3];
    const float* bk = (const float*)d_in[4];
    const float* Wv = (const float*)d_in[5];
    const float* bv = (const float*)d_in[6];
    const float* Wo = (const float*)d_in[7];
    const float* bo = (const float*)d_in[8];

    const size_t MB = 1u << 20;
    if (ws_size < 40 * MB) return;   // need 40MB scratch
    char* ws = (char*)d_ws;
    u16* xb    = (u16*)(ws);             // 8MB  [4096][1024] bf16 (also reused as ao)
    u16* wqkvt = (u16*)(ws + 8 * MB);    // 6MB  [3072][1024] = [Wq^T;Wk^T;Wv^T]
    u16* wot   = (u16*)(ws + 14 * MB);   // 2MB  Wo^T
    u16* qb    = (u16*)(ws + 16 * MB);   // 8MB  [32][2048][64]
    u16* kb    = (u16*)(ws + 24 * MB);   // 8MB  [32][2048][64]
    u16* vt    = (u16*)(ws + 32 * MB);   // 8MB  [32][64][2048]
    u16* ao    = xb;                     // reuse: xb dead after QKV GEMM

    cvt_x_k<<<2048, 256, 0, stream>>>(x, xb);
    cvt_wT_k<<<dim3(16, 16), 256, 0, stream>>>(Wq, wqkvt);
    cvt_wT_k<<<dim3(16, 16), 256, 0, stream>>>(Wk, wqkvt + (1u << 20));
    cvt_wT_k<<<dim3(16, 16), 256, 0, stream>>>(Wv, wqkvt + (2u << 20));
    cvt_wT_k<<<dim3(16, 16), 256, 0, stream>>>(Wo, wot);

    gemm_k<0><<<dim3(32, 24), 256, 0, stream>>>(xb, wqkvt, bq, bk, bv,
                                                qb, kb, vt, nullptr);
    attn_k<<<dim3(32, 32), 256, 0, stream>>>(qb, kb, vt, ao);
    gemm_k<1><<<dim3(32, 8), 256, 0, stream>>>(ao, wot, bo, nullptr, nullptr,
                                               nullptr, nullptr, nullptr,
                                               (float*)d_out);
}

// Round 3
// 200.363 us; speedup vs baseline: 1.1477x; 1.1477x over previous
//
#include <hip/hip_runtime.h>
#include <cstdint>
#include <cstddef>

typedef unsigned short u16;
typedef unsigned int u32;
typedef __bf16 bf16x8 __attribute__((ext_vector_type(8)));
typedef float f32x4 __attribute__((ext_vector_type(4)));
typedef u32 u32x4 __attribute__((ext_vector_type(4)));
typedef unsigned short u16x8 __attribute__((ext_vector_type(8)));

// f32 -> bf16 round-to-nearest-even (finite inputs only)
__device__ __forceinline__ u16 f2bf(float f) {
    u32 u = __float_as_uint(f);
    u += 0x7fffu + ((u >> 16) & 1u);
    return (u16)(u >> 16);
}

// async global->LDS, 16B per lane. LDS ptr must be wave-uniform; HW adds lane*16.
__device__ __forceinline__ void gl16(const void* g, void* l) {
    __builtin_amdgcn_global_load_lds(
        (const __attribute__((address_space(1))) unsigned int*)g,
        (__attribute__((address_space(3))) unsigned int*)l, 16, 0, 0);
}

// ---------------------------------------------------------------- conversions
__global__ __launch_bounds__(256) void cvt_x_k(const float* __restrict__ x,
                                               u16* __restrict__ o) {
    int i = blockIdx.x * 256 + threadIdx.x;
    const float4* xv = (const float4*)x;
    float4 a = xv[2 * i], b = xv[2 * i + 1];
    ushort4 r0, r1;
    r0.x = f2bf(a.x); r0.y = f2bf(a.y); r0.z = f2bf(a.z); r0.w = f2bf(a.w);
    r1.x = f2bf(b.x); r1.y = f2bf(b.y); r1.z = f2bf(b.z); r1.w = f2bf(b.w);
    ((ushort4*)o)[2 * i] = r0;
    ((ushort4*)o)[2 * i + 1] = r1;
}

// W [1024][1024] f32 row-major (k,n) -> out [1024][1024] bf16 (n,k)  (i.e. W^T)
__global__ __launch_bounds__(256) void cvt_wT_k(const float* __restrict__ W,
                                                u16* __restrict__ o) {
    __shared__ float tile[64][65];
    const int bx = blockIdx.x, by = blockIdx.y;
    const int t = threadIdx.x, tn = t & 63, tr = t >> 6;
#pragma unroll
    for (int r = 0; r < 16; ++r) {
        int kk = r * 4 + tr;
        tile[kk][tn] = W[(size_t)(by * 64 + kk) * 1024 + bx * 64 + tn];
    }
    __syncthreads();
#pragma unroll
    for (int r = 0; r < 16; ++r) {
        int nn = r * 4 + tr;
        o[(size_t)(bx * 64 + nn) * 1024 + by * 64 + tn] = f2bf(tile[tn][nn]);
    }
}

// ---------------------------------------------------------------- GEMM 128x128
// A [M][1024] bf16 row-major, Bt [N][1024] bf16 (= B^T), K=1024.
// MODE 0: fused QKV epilogue -> q (pre-scaled by 0.125*log2e), k as
//         [BH][2048][64], v transposed [BH][64][2048]
// MODE 1: f32 out [M][1024] + bias
template <int MODE>
__global__ __launch_bounds__(256) void gemm_k(
    const u16* __restrict__ A, const u16* __restrict__ Bt,
    const float* __restrict__ bias0, const float* __restrict__ bias1,
    const float* __restrict__ bias2,
    u16* __restrict__ oq, u16* __restrict__ ok_, u16* __restrict__ ov,
    float* __restrict__ oc) {
    __shared__ __align__(16) u16 As[128 * 32];
    __shared__ __align__(16) u16 Bs[128 * 32];
    const int t = threadIdx.x, w = t >> 6, lane = t & 63;
    const int lr = lane & 15, lg = lane >> 4;
    const int brow = blockIdx.x * 128, bcol = blockIdx.y * 128;
    const int wr = w >> 1, wc = w & 1;
    const char* Ab = (const char*)A + (size_t)brow * 2048;
    const char* Bb = (const char*)Bt + (size_t)bcol * 2048;
    char* AsB = (char*)As;
    char* BsB = (char*)Bs;
    const int lrow = lane >> 2, lcol = (lane & 3) << 4;
    f32x4 acc[4][4];
#pragma unroll
    for (int m = 0; m < 4; ++m)
#pragma unroll
        for (int n = 0; n < 4; ++n) acc[m][n] = (f32x4){0.f, 0.f, 0.f, 0.f};

    for (int k0 = 0; k0 < 1024; k0 += 32) {
#pragma unroll
        for (int i = 0; i < 2; ++i) {
            int r0 = w * 32 + i * 16;
            gl16(Ab + (size_t)(r0 + lrow) * 2048 + k0 * 2 + lcol, AsB + r0 * 64);
            gl16(Bb + (size_t)(r0 + lrow) * 2048 + k0 * 2 + lcol, BsB + r0 * 64);
        }
        __syncthreads();
        bf16x8 af[4], bfr[4];
#pragma unroll
        for (int m = 0; m < 4; ++m)
            af[m] = *(const bf16x8*)(AsB + (wr * 64 + m * 16 + lr) * 64 + lg * 16);
#pragma unroll
        for (int n = 0; n < 4; ++n)
            bfr[n] = *(const bf16x8*)(BsB + (wc * 64 + n * 16 + lr) * 64 + lg * 16);
#pragma unroll
        for (int m = 0; m < 4; ++m)
#pragma unroll
            for (int n = 0; n < 4; ++n)
                acc[m][n] = __builtin_amdgcn_mfma_f32_16x16x32_bf16(af[m], bfr[n],
                                                                    acc[m][n], 0, 0, 0);
        __syncthreads();
    }

    const float QSCALE = 0.125f * 1.44269504f;
#pragma unroll
    for (int n = 0; n < 4; ++n) {
        const int col = bcol + wc * 64 + n * 16 + lr;
        if (MODE == 0) {
#pragma unroll
            for (int m = 0; m < 4; ++m)
#pragma unroll
                for (int r = 0; r < 4; ++r) {
                    int row = brow + wr * 64 + m * 16 + 4 * lg + r;
                    int b = row >> 11, l = row & 2047;
                    float val = acc[m][n][r];
                    if (col < 1024) {
                        int hh = col >> 6, d = col & 63;
                        oq[(((size_t)b * 16 + hh) * 2048 + l) * 64 + d] =
                            f2bf((val + bias0[col]) * QSCALE);
                    } else if (col < 2048) {
                        int c = col - 1024, hh = c >> 6, d = c & 63;
                        ok_[(((size_t)b * 16 + hh) * 2048 + l) * 64 + d] =
                            f2bf(val + bias1[c]);
                    } else {
                        int c = col - 2048, hh = c >> 6, d = c & 63;
                        ov[(((size_t)b * 16 + hh) * 64 + d) * 2048 + l] =
                            f2bf(val + bias2[c]);
                    }
                }
        } else {
            const float bb = bias0[col];
#pragma unroll
            for (int m = 0; m < 4; ++m)
#pragma unroll
                for (int r = 0; r < 4; ++r) {
                    int row = brow + wr * 64 + m * 16 + 4 * lg + r;
                    oc[(size_t)row * 1024 + col] = acc[m][n][r] + bb;
                }
        }
    }
}

// ---------------------------------------------------------------- attention
// q (pre-scaled), k: [BH][2048][64] bf16; vt: [BH][64][2048] bf16 (V^T per head)
// ao:  [B*2048][1024] bf16
// Swapped-operand scheme: S^T = mfma(K,Q) -> lane owns q=lane&15, j in regs.
// O^T = mfma(V^T, P) -> per-lane scalar m,l; epilogue transpose via LDS.
__global__ __launch_bounds__(256, 4) void attn_k(const u16* __restrict__ qg_,
                                                 const u16* __restrict__ kg_,
                                                 const u16* __restrict__ vg_,
                                                 u16* __restrict__ ao) {
    __shared__ __align__(16) u16 smem[3 * 64 * 64];   // Qt | Kt | Vt (24KB)
    char* QtB = (char*)smem;
    char* KtB = (char*)smem + 8192;
    char* VtB = (char*)smem + 16384;
    const int t = threadIdx.x, w = t >> 6, lane = t & 63;
    const int lr = lane & 15, lg = lane >> 4;
    // XCD swizzle: blocks sharing bh land on one XCD (bid%8 groups)
    const int bid = blockIdx.y * 32 + blockIdx.x;
    const int qt = (bid >> 3) & 31;
    const int bh = ((bid >> 8) << 3) | (bid & 7);
    const int q0 = qt * 64, h = bh & 15, bb = bh >> 4;
    const float sl2 = exp2f(-0.5f * (float)(h + 1)) * 1.44269504f; // slope*log2e

    // hoisted staging offsets (XOR-swizzled source, linear LDS dest)
    const int U0 = (w * 2 + 0) * 64 + lane, U1 = U0 + 64;
    const int rr0 = U0 >> 3, u0 = U0 & 7, rr1 = U1 >> 3, u1 = U1 & 7;
    const int koff0 = rr0 * 128 + ((u0 ^ (rr0 & 7)) << 4);
    const int koff1 = rr1 * 128 + ((u1 ^ (rr1 & 7)) << 4);
    const int voff0 = rr0 * 4096 + ((u0 ^ (rr0 & 7)) << 4);
    const int voff1 = rr1 * 4096 + ((u1 ^ (rr1 & 7)) << 4);
    const int lds0 = (w * 2 + 0) * 1024, lds1 = (w * 2 + 1) * 1024;

    // stage Q tile
    const char* qsrc = (const char*)(qg_ + ((size_t)bh * 2048 + q0) * 64);
    gl16(qsrc + koff0, QtB + lds0);
    gl16(qsrc + koff1, QtB + lds1);
    __syncthreads();
    bf16x8 qa[2];
#pragma unroll
    for (int kk = 0; kk < 2; ++kk)
        qa[kk] = *(const bf16x8*)(QtB + (w * 16 + lr) * 128 +
                                  (((kk * 4 + lg) ^ (lr & 7)) << 4));

    float m = -3.0e38f, l = 0.f;
    f32x4 oacc[4];
#pragma unroll
    for (int nn = 0; nn < 4; ++nn) oacc[nn] = (f32x4){0.f, 0.f, 0.f, 0.f};

    // incremental ALiBi (base-2 domain): ab[n][r] = sl2*(j - q), j at j0=0
    float ab[4][4];
#pragma unroll
    for (int n = 0; n < 4; ++n)
#pragma unroll
        for (int r = 0; r < 4; ++r)
            ab[n][r] = sl2 * (float)(n * 16 + 4 * lg + r - (q0 + w * 16 + lr));
    const float ainc = sl2 * 64.0f;

    const char* khead = (const char*)(kg_ + (size_t)bh * 2048 * 64);
    const char* vhead = (const char*)(vg_ + (size_t)bh * 64 * 2048);
    // P-exchange source lanes: word g<2 from srcA, g>=2 from srcB
    const int srcA = lr + ((lg & 1) << 5);
    const int srcB = srcA + 16;
    const bool hiHalf = (lg >> 1) != 0;

    for (int j0 = 0; j0 < 2048; j0 += 64) {
        gl16(khead + (size_t)j0 * 128 + koff0, KtB + lds0);
        gl16(khead + (size_t)j0 * 128 + koff1, KtB + lds1);
        gl16(vhead + (size_t)j0 * 2 + voff0, VtB + lds0);
        gl16(vhead + (size_t)j0 * 2 + voff1, VtB + lds1);
        __syncthreads();

        // S^T = mfma(K, Q): lane holds S[j=j0+n*16+4lg+r][q=lr]
        f32x4 sa[4];
#pragma unroll
        for (int n = 0; n < 4; ++n) sa[n] = (f32x4){0.f, 0.f, 0.f, 0.f};
#pragma unroll
        for (int kk = 0; kk < 2; ++kk)
#pragma unroll
            for (int n = 0; n < 4; ++n) {
                bf16x8 kf = *(const bf16x8*)(KtB + (n * 16 + lr) * 128 +
                                             (((kk * 4 + lg) ^ (lr & 7)) << 4));
                sa[n] = __builtin_amdgcn_mfma_f32_16x16x32_bf16(kf, qa[kk], sa[n],
                                                                0, 0, 0);
            }

        // per-lane softmax over 16 regs + 2-shfl reduce across lg groups
        float p[4][4], mloc = -3.0e38f;
#pragma unroll
        for (int n = 0; n < 4; ++n)
#pragma unroll
            for (int r = 0; r < 4; ++r) {
                float s = sa[n][r] + ab[n][r];
                p[n][r] = s;
                mloc = fmaxf(mloc, s);
                ab[n][r] += ainc;
            }
        mloc = fmaxf(mloc, __shfl_xor(mloc, 16));
        mloc = fmaxf(mloc, __shfl_xor(mloc, 32));
        const float mnew = fmaxf(m, mloc);
        const float corr = exp2f(m - mnew);
        m = mnew;
        float ls = 0.f;
#pragma unroll
        for (int n = 0; n < 4; ++n)
#pragma unroll
            for (int r = 0; r < 4; ++r) {
                float e = exp2f(p[n][r] - mnew);
                p[n][r] = e;
                ls += e;
            }
        ls += __shfl_xor(ls, 16);
        ls += __shfl_xor(ls, 32);
        l = l * corr + ls;
#pragma unroll
        for (int nn = 0; nn < 4; ++nn) oacc[nn] *= corr;

        // pack P^T -> bf16 pairs (pk[n*2+rp] = {p[n][2rp], p[n][2rp+1]})
        u32 pk[8];
#pragma unroll
        for (int n = 0; n < 4; ++n)
#pragma unroll
            for (int rp = 0; rp < 2; ++rp) {
                u32 rpk;
                asm("v_cvt_pk_bf16_f32 %0, %1, %2"
                    : "=v"(rpk) : "v"(p[n][2 * rp]), "v"(p[n][2 * rp + 1]));
                pk[n * 2 + rp] = rpk;
            }
        // exchange to B-frag layout: dest (lr,lg), frag kk, word g needs
        //   pk[(kk*2 + (lg>>1))*2 + (g&1)]  from lane 16*((lg&1)*2+(g>>1))+lr.
        // Register index must be compile-time at the SOURCE -> shfl both n
        // candidates (constant indices) and select by dest's lg>>1.
        u32x4 pb0, pb1;
#pragma unroll
        for (int g = 0; g < 4; ++g) {
            int src = (g < 2) ? srcA : srcB;
            u32 a0 = (u32)__shfl((int)pk[0 + (g & 1)], src);
            u32 a1 = (u32)__shfl((int)pk[2 + (g & 1)], src);
            u32 b0 = (u32)__shfl((int)pk[4 + (g & 1)], src);
            u32 b1 = (u32)__shfl((int)pk[6 + (g & 1)], src);
            pb0[g] = hiHalf ? a1 : a0;
            pb1[g] = hiHalf ? b1 : b0;
        }
        bf16x8 pf0 = __builtin_bit_cast(bf16x8, pb0);
        bf16x8 pf1 = __builtin_bit_cast(bf16x8, pb1);

        // O^T += mfma(V^T, P): oacc[nn][r] = O[q=lr][d=nn*16+4lg+r]
#pragma unroll
        for (int nn = 0; nn < 4; ++nn) {
            bf16x8 vf0 = *(const bf16x8*)(VtB + (nn * 16 + lr) * 128 +
                                          ((lg ^ (lr & 7)) << 4));
            oacc[nn] = __builtin_amdgcn_mfma_f32_16x16x32_bf16(vf0, pf0, oacc[nn],
                                                               0, 0, 0);
            bf16x8 vf1 = *(const bf16x8*)(VtB + (nn * 16 + lr) * 128 +
                                          (((4 + lg) ^ (lr & 7)) << 4));
            oacc[nn] = __builtin_amdgcn_mfma_f32_16x16x32_bf16(vf1, pf1, oacc[nn],
                                                               0, 0, 0);
        }
        __syncthreads();
    }

    // epilogue: normalize, transpose O^T -> O via LDS (stride-72 rows), store
    const float linv = 1.0f / l;
    u16* ow = smem + w * (16 * 72);
#pragma unroll
    for (int nn = 0; nn < 4; ++nn)
#pragma unroll
        for (int r = 0; r < 4; ++r)
            ow[lr * 72 + nn * 16 + 4 * lg + r] = f2bf(oacc[nn][r] * linv);
    __syncthreads();
    const int q_ = lane >> 2, d0 = (lane & 3) << 4;
    const u16* orow = smem + w * (16 * 72) + q_ * 72 + d0;
    u16x8 o0 = *(const u16x8*)(orow);
    u16x8 o1 = *(const u16x8*)(orow + 8);
    size_t gaddr = ((size_t)bb * 2048 + q0 + w * 16 + q_) * 1024 + h * 64 + d0;
    *(u16x8*)(ao + gaddr) = o0;
    *(u16x8*)(ao + gaddr + 8) = o1;
}

// ---------------------------------------------------------------- launch
extern "C" void kernel_launch(void* const* d_in, const int* in_sizes, int n_in,
                              void* d_out, int out_size, void* d_ws, size_t ws_size,
                              hipStream_t stream) {
    const float* x  = (const float*)d_in[0];
    const float* Wq = (const float*)d_in[1];
    const float* bq = (const float*)d_in[2];
    const float* Wk = (const float*)d_in[3];
    const float* bk = (const float*)d_in[4];
    const float* Wv = (const float*)d_in[5];
    const float* bv = (const float*)d_in[6];
    const float* Wo = (const float*)d_in[7];
    const float* bo = (const float*)d_in[8];

    const size_t MB = 1u << 20;
    if (ws_size < 40 * MB) return;
    char* ws = (char*)d_ws;
    u16* xb    = (u16*)(ws);             // 8MB  [4096][1024] bf16 (reused as ao)
    u16* wqkvt = (u16*)(ws + 8 * MB);    // 6MB  [3072][1024] = [Wq^T;Wk^T;Wv^T]
    u16* wot   = (u16*)(ws + 14 * MB);   // 2MB  Wo^T
    u16* qb    = (u16*)(ws + 16 * MB);   // 8MB  [32][2048][64]
    u16* kb    = (u16*)(ws + 24 * MB);   // 8MB  [32][2048][64]
    u16* vt    = (u16*)(ws + 32 * MB);   // 8MB  [32][64][2048]
    u16* ao    = xb;

    cvt_x_k<<<2048, 256, 0, stream>>>(x, xb);
    cvt_wT_k<<<dim3(16, 16), 256, 0, stream>>>(Wq, wqkvt);
    cvt_wT_k<<<dim3(16, 16), 256, 0, stream>>>(Wk, wqkvt + (1u << 20));
    cvt_wT_k<<<dim3(16, 16), 256, 0, stream>>>(Wv, wqkvt + (2u << 20));
    cvt_wT_k<<<dim3(16, 16), 256, 0, stream>>>(Wo, wot);

    gemm_k<0><<<dim3(32, 24), 256, 0, stream>>>(xb, wqkvt, bq, bk, bv,
                                                qb, kb, vt, nullptr);
    attn_k<<<dim3(32, 32), 256, 0, stream>>>(qb, kb, vt, ao);
    gemm_k<1><<<dim3(32, 8), 256, 0, stream>>>(ao, wot, bo, nullptr, nullptr,
                                               nullptr, nullptr, nullptr,
                                               (float*)d_out);
}

// Round 4
// 192.738 us; speedup vs baseline: 1.1931x; 1.0396x over previous
//
#include <hip/hip_runtime.h>
#include <cstdint>
#include <cstddef>

typedef unsigned short u16;
typedef unsigned int u32;
typedef __bf16 bf16x8 __attribute__((ext_vector_type(8)));
typedef float f32x4 __attribute__((ext_vector_type(4)));
typedef u32 u32x4 __attribute__((ext_vector_type(4)));
typedef unsigned short u16x8 __attribute__((ext_vector_type(8)));

// f32 -> bf16 round-to-nearest-even (finite inputs only)
__device__ __forceinline__ u16 f2bf(float f) {
    u32 u = __float_as_uint(f);
    u += 0x7fffu + ((u >> 16) & 1u);
    return (u16)(u >> 16);
}

// async global->LDS, 16B per lane. LDS ptr must be wave-uniform; HW adds lane*16.
__device__ __forceinline__ void gl16(const void* g, void* l) {
    __builtin_amdgcn_global_load_lds(
        (const __attribute__((address_space(1))) unsigned int*)g,
        (__attribute__((address_space(3))) unsigned int*)l, 16, 0, 0);
}

// ---------------------------------------------------------------- conversions
__global__ __launch_bounds__(256) void cvt_x_k(const float* __restrict__ x,
                                               u16* __restrict__ o) {
    int i = blockIdx.x * 256 + threadIdx.x;
    const float4* xv = (const float4*)x;
    float4 a = xv[2 * i], b = xv[2 * i + 1];
    ushort4 r0, r1;
    r0.x = f2bf(a.x); r0.y = f2bf(a.y); r0.z = f2bf(a.z); r0.w = f2bf(a.w);
    r1.x = f2bf(b.x); r1.y = f2bf(b.y); r1.z = f2bf(b.z); r1.w = f2bf(b.w);
    ((ushort4*)o)[2 * i] = r0;
    ((ushort4*)o)[2 * i + 1] = r1;
}

// W [1024][1024] f32 row-major (k,n) -> out [1024][1024] bf16 (n,k)  (i.e. W^T)
__global__ __launch_bounds__(256) void cvt_wT_k(const float* __restrict__ W,
                                                u16* __restrict__ o) {
    __shared__ float tile[64][65];
    const int bx = blockIdx.x, by = blockIdx.y;
    const int t = threadIdx.x, tn = t & 63, tr = t >> 6;
#pragma unroll
    for (int r = 0; r < 16; ++r) {
        int kk = r * 4 + tr;
        tile[kk][tn] = W[(size_t)(by * 64 + kk) * 1024 + bx * 64 + tn];
    }
    __syncthreads();
#pragma unroll
    for (int r = 0; r < 16; ++r) {
        int nn = r * 4 + tr;
        o[(size_t)(bx * 64 + nn) * 1024 + by * 64 + tn] = f2bf(tile[tn][nn]);
    }
}

// ---------------------------------------------------------------- GEMM 128x128
// A [M][1024] bf16 row-major, Bt [N][1024] bf16 (= B^T), K=1024.
// MODE 0: fused QKV epilogue -> q (pre-scaled by 0.125*log2e), k as
//         [BH][2048][64], v transposed [BH][64][2048]
// MODE 1: f32 out [M][1024] + bias
template <int MODE>
__global__ __launch_bounds__(256) void gemm_k(
    const u16* __restrict__ A, const u16* __restrict__ Bt,
    const float* __restrict__ bias0, const float* __restrict__ bias1,
    const float* __restrict__ bias2,
    u16* __restrict__ oq, u16* __restrict__ ok_, u16* __restrict__ ov,
    float* __restrict__ oc) {
    __shared__ __align__(16) u16 As[128 * 32];
    __shared__ __align__(16) u16 Bs[128 * 32];
    const int t = threadIdx.x, w = t >> 6, lane = t & 63;
    const int lr = lane & 15, lg = lane >> 4;
    const int brow = blockIdx.x * 128, bcol = blockIdx.y * 128;
    const int wr = w >> 1, wc = w & 1;
    const char* Ab = (const char*)A + (size_t)brow * 2048;
    const char* Bb = (const char*)Bt + (size_t)bcol * 2048;
    char* AsB = (char*)As;
    char* BsB = (char*)Bs;
    const int lrow = lane >> 2, lcol = (lane & 3) << 4;
    f32x4 acc[4][4];
#pragma unroll
    for (int m = 0; m < 4; ++m)
#pragma unroll
        for (int n = 0; n < 4; ++n) acc[m][n] = (f32x4){0.f, 0.f, 0.f, 0.f};

    for (int k0 = 0; k0 < 1024; k0 += 32) {
#pragma unroll
        for (int i = 0; i < 2; ++i) {
            int r0 = w * 32 + i * 16;
            gl16(Ab + (size_t)(r0 + lrow) * 2048 + k0 * 2 + lcol, AsB + r0 * 64);
            gl16(Bb + (size_t)(r0 + lrow) * 2048 + k0 * 2 + lcol, BsB + r0 * 64);
        }
        __syncthreads();
        bf16x8 af[4], bfr[4];
#pragma unroll
        for (int m = 0; m < 4; ++m)
            af[m] = *(const bf16x8*)(AsB + (wr * 64 + m * 16 + lr) * 64 + lg * 16);
#pragma unroll
        for (int n = 0; n < 4; ++n)
            bfr[n] = *(const bf16x8*)(BsB + (wc * 64 + n * 16 + lr) * 64 + lg * 16);
#pragma unroll
        for (int m = 0; m < 4; ++m)
#pragma unroll
            for (int n = 0; n < 4; ++n)
                acc[m][n] = __builtin_amdgcn_mfma_f32_16x16x32_bf16(af[m], bfr[n],
                                                                    acc[m][n], 0, 0, 0);
        __syncthreads();
    }

    const float QSCALE = 0.125f * 1.44269504f;
#pragma unroll
    for (int n = 0; n < 4; ++n) {
        const int col = bcol + wc * 64 + n * 16 + lr;
        if (MODE == 0) {
#pragma unroll
            for (int m = 0; m < 4; ++m)
#pragma unroll
                for (int r = 0; r < 4; ++r) {
                    int row = brow + wr * 64 + m * 16 + 4 * lg + r;
                    int b = row >> 11, l = row & 2047;
                    float val = acc[m][n][r];
                    if (col < 1024) {
                        int hh = col >> 6, d = col & 63;
                        oq[(((size_t)b * 16 + hh) * 2048 + l) * 64 + d] =
                            f2bf((val + bias0[col]) * QSCALE);
                    } else if (col < 2048) {
                        int c = col - 1024, hh = c >> 6, d = c & 63;
                        ok_[(((size_t)b * 16 + hh) * 2048 + l) * 64 + d] =
                            f2bf(val + bias1[c]);
                    } else {
                        int c = col - 2048, hh = c >> 6, d = c & 63;
                        ov[(((size_t)b * 16 + hh) * 64 + d) * 2048 + l] =
                            f2bf(val + bias2[c]);
                    }
                }
        } else {
            const float bb = bias0[col];
#pragma unroll
            for (int m = 0; m < 4; ++m)
#pragma unroll
                for (int r = 0; r < 4; ++r) {
                    int row = brow + wr * 64 + m * 16 + 4 * lg + r;
                    oc[(size_t)row * 1024 + col] = acc[m][n][r] + bb;
                }
        }
    }
}

// ---------------------------------------------------------------- attention
// q (pre-scaled), k: [BH][2048][64] bf16; vt: [BH][64][2048] bf16 (V^T per head)
// ao:  [B*2048][1024] bf16
// Swapped-operand scheme: S^T = mfma(K,Q) with ALiBi in the MFMA C-init.
// Double-buffered K/V, one raw barrier per tile. Defer-max (THR=8 exp2-domain).
__global__ __launch_bounds__(256, 4) void attn_k(const u16* __restrict__ qg_,
                                                 const u16* __restrict__ kg_,
                                                 const u16* __restrict__ vg_,
                                                 u16* __restrict__ ao) {
    __shared__ __align__(16) u16 smem[20480];   // 40KB: Q|K0|K1|V0|V1 (8KB each)
    char* QtB = (char*)smem;
    char* K0 = (char*)smem + 8192;    // K1 at +16384
    char* V0 = (char*)smem + 24576;   // V1 at +32768
    const int t = threadIdx.x, w = t >> 6, lane = t & 63;
    const int lr = lane & 15, lg = lane >> 4;
    // XCD swizzle: blocks sharing bh land on one XCD (bid%8 groups)
    const int bid = blockIdx.y * 32 + blockIdx.x;
    const int qt = (bid >> 3) & 31;
    const int bh = ((bid >> 8) << 3) | (bid & 7);
    const int q0 = qt * 64, h = bh & 15, bb = bh >> 4;
    const float sl2 = exp2f(-0.5f * (float)(h + 1)) * 1.44269504f; // slope*log2e

    // hoisted staging offsets (XOR-swizzled source, linear LDS dest)
    const int U0 = (w * 2 + 0) * 64 + lane, U1 = U0 + 64;
    const int rr0 = U0 >> 3, u0 = U0 & 7, rr1 = U1 >> 3, u1 = U1 & 7;
    const int koff0 = rr0 * 128 + ((u0 ^ (rr0 & 7)) << 4);
    const int koff1 = rr1 * 128 + ((u1 ^ (rr1 & 7)) << 4);
    const int voff0 = rr0 * 4096 + ((u0 ^ (rr0 & 7)) << 4);
    const int voff1 = rr1 * 4096 + ((u1 ^ (rr1 & 7)) << 4);
    const int lds0 = (w * 2 + 0) * 1024, lds1 = (w * 2 + 1) * 1024;

    const char* qsrc = (const char*)(qg_ + ((size_t)bh * 2048 + q0) * 64);
    const char* khead = (const char*)(kg_ + (size_t)bh * 2048 * 64);
    const char* vhead = (const char*)(vg_ + (size_t)bh * 64 * 2048);

    // prologue: stage Q + tile 0 (6 loads), overlap setup VALU, then drain
    gl16(qsrc + koff0, QtB + lds0);
    gl16(qsrc + koff1, QtB + lds1);
    gl16(khead + koff0, K0 + lds0);
    gl16(khead + koff1, K0 + lds1);
    gl16(vhead + voff0, V0 + lds0);
    gl16(vhead + voff1, V0 + lds1);

    // iter-invariant ALiBi base: abF[n][r] = sl2*(jloc - qabs), jloc = n*16+4lg+r
    f32x4 abF[4];
#pragma unroll
    for (int n = 0; n < 4; ++n)
#pragma unroll
        for (int r = 0; r < 4; ++r)
            abF[n][r] = sl2 * (float)(n * 16 + 4 * lg + r - (q0 + w * 16 + lr));
    const float ainc = sl2 * 64.0f;
    float scalJ = 0.f;                 // sl2 * j0
    float m = -3.0e38f, l = 0.f;       // l: per-lane partial (reduced at end)
    f32x4 oacc[4];
#pragma unroll
    for (int nn = 0; nn < 4; ++nn) oacc[nn] = (f32x4){0.f, 0.f, 0.f, 0.f};
    // P-exchange source lanes: word g<2 from srcA, g>=2 from srcB
    const int srcA = lr + ((lg & 1) << 5);
    const int srcB = srcA + 16;
    const bool hiHalf = (lg >> 1) != 0;

    asm volatile("s_waitcnt vmcnt(0)" ::: "memory");
    __builtin_amdgcn_s_barrier();
    __builtin_amdgcn_sched_barrier(0);

    bf16x8 qa[2];
#pragma unroll
    for (int kk = 0; kk < 2; ++kk)
        qa[kk] = *(const bf16x8*)(QtB + (w * 16 + lr) * 128 +
                                  (((kk * 4 + lg) ^ (lr & 7)) << 4));

    for (int tt = 0; tt < 32; ++tt) {
        char* Kc = K0 + (tt & 1) * 8192;
        char* Vc = V0 + (tt & 1) * 8192;
        if (tt < 31) {   // stage next tile into the other buffer
            const char* ks = khead + (size_t)(tt + 1) * 64 * 128;
            const char* vs = vhead + (size_t)(tt + 1) * 64 * 2;
            char* Kn = K0 + ((tt + 1) & 1) * 8192;
            char* Vn = V0 + ((tt + 1) & 1) * 8192;
            gl16(ks + koff0, Kn + lds0);
            gl16(ks + koff1, Kn + lds1);
            gl16(vs + voff0, Vn + lds0);
            gl16(vs + voff1, Vn + lds1);
        }

        // S^T = mfma(K, Q) + ALiBi-base as C-init: lane has S[j][q=lr]+abF
        f32x4 sa[4];
        __builtin_amdgcn_s_setprio(1);
#pragma unroll
        for (int n = 0; n < 4; ++n) {
            bf16x8 kf = *(const bf16x8*)(Kc + (n * 16 + lr) * 128 +
                                         ((lg ^ (lr & 7)) << 4));
            sa[n] = __builtin_amdgcn_mfma_f32_16x16x32_bf16(kf, qa[0], abF[n],
                                                            0, 0, 0);
        }
#pragma unroll
        for (int n = 0; n < 4; ++n) {
            bf16x8 kf = *(const bf16x8*)(Kc + (n * 16 + lr) * 128 +
                                         (((4 + lg) ^ (lr & 7)) << 4));
            sa[n] = __builtin_amdgcn_mfma_f32_16x16x32_bf16(kf, qa[1], sa[n],
                                                            0, 0, 0);
        }
        __builtin_amdgcn_s_setprio(0);

        // max over 16 regs (tree) + cross-group reduce (q-column uniform)
        float m0 = fmaxf(fmaxf(sa[0][0], sa[0][1]), fmaxf(sa[0][2], sa[0][3]));
        float m1 = fmaxf(fmaxf(sa[1][0], sa[1][1]), fmaxf(sa[1][2], sa[1][3]));
        float m2 = fmaxf(fmaxf(sa[2][0], sa[2][1]), fmaxf(sa[2][2], sa[2][3]));
        float m3 = fmaxf(fmaxf(sa[3][0], sa[3][1]), fmaxf(sa[3][2], sa[3][3]));
        float mloc = fmaxf(fmaxf(m0, m1), fmaxf(m2, m3));
        mloc = fmaxf(mloc, __shfl_xor(mloc, 16));
        mloc = fmaxf(mloc, __shfl_xor(mloc, 32));
        const float mlocAbs = mloc + scalJ;

        // defer-max: only rescale when max grew by > 8 (exp2 domain)
        if (!__all(mlocAbs - m <= 8.0f)) {
            const float mnew = fmaxf(m, mlocAbs);
            const float corr = exp2f(m - mnew);
            m = mnew;
            l *= corr;
#pragma unroll
            for (int nn = 0; nn < 4; ++nn) oacc[nn] *= corr;
        }
        const float mrel = m - scalJ;
        scalJ += ainc;

        float ls = 0.f;
#pragma unroll
        for (int n = 0; n < 4; ++n)
#pragma unroll
            for (int r = 0; r < 4; ++r) {
                float e = exp2f(sa[n][r] - mrel);
                sa[n][r] = e;
                ls += e;
            }
        l += ls;

        // pack P^T -> bf16 pairs (pk[n*2+rp] = {p[n][2rp], p[n][2rp+1]})
        u32 pk[8];
#pragma unroll
        for (int n = 0; n < 4; ++n)
#pragma unroll
            for (int rp = 0; rp < 2; ++rp) {
                u32 rpk;
                asm("v_cvt_pk_bf16_f32 %0, %1, %2"
                    : "=v"(rpk) : "v"(sa[n][2 * rp]), "v"(sa[n][2 * rp + 1]));
                pk[n * 2 + rp] = rpk;
            }
        // exchange to B-frag layout: dest (lr,lg), frag kk, word g needs
        //   pk[(kk*2 + (lg>>1))*2 + (g&1)]  from lane 16*((lg&1)*2+(g>>1))+lr.
        u32x4 pb0, pb1;
#pragma unroll
        for (int g = 0; g < 4; ++g) {
            int src = (g < 2) ? srcA : srcB;
            u32 a0 = (u32)__shfl((int)pk[0 + (g & 1)], src);
            u32 a1 = (u32)__shfl((int)pk[2 + (g & 1)], src);
            u32 b0 = (u32)__shfl((int)pk[4 + (g & 1)], src);
            u32 b1 = (u32)__shfl((int)pk[6 + (g & 1)], src);
            pb0[g] = hiHalf ? a1 : a0;
            pb1[g] = hiHalf ? b1 : b0;
        }
        bf16x8 pf0 = __builtin_bit_cast(bf16x8, pb0);
        bf16x8 pf1 = __builtin_bit_cast(bf16x8, pb1);

        // O^T += mfma(V^T, P): oacc[nn][r] = O[q=lr][d=nn*16+4lg+r]
        __builtin_amdgcn_s_setprio(1);
#pragma unroll
        for (int nn = 0; nn < 4; ++nn) {
            bf16x8 vf0 = *(const bf16x8*)(Vc + (nn * 16 + lr) * 128 +
                                          ((lg ^ (lr & 7)) << 4));
            oacc[nn] = __builtin_amdgcn_mfma_f32_16x16x32_bf16(vf0, pf0, oacc[nn],
                                                               0, 0, 0);
            bf16x8 vf1 = *(const bf16x8*)(Vc + (nn * 16 + lr) * 128 +
                                          (((4 + lg) ^ (lr & 7)) << 4));
            oacc[nn] = __builtin_amdgcn_mfma_f32_16x16x32_bf16(vf1, pf1, oacc[nn],
                                                               0, 0, 0);
        }
        __builtin_amdgcn_s_setprio(0);

        // drain next-tile loads (issued before compute -> latency hidden)
        asm volatile("s_waitcnt vmcnt(0)" ::: "memory");
        __builtin_amdgcn_s_barrier();
        __builtin_amdgcn_sched_barrier(0);
    }

    // epilogue: finish l reduction, normalize, transpose O^T -> O via LDS
    l += __shfl_xor(l, 16);
    l += __shfl_xor(l, 32);
    const float linv = 1.0f / l;
    u16* ow = smem + w * (16 * 72);
#pragma unroll
    for (int nn = 0; nn < 4; ++nn)
#pragma unroll
        for (int r = 0; r < 4; ++r)
            ow[lr * 72 + nn * 16 + 4 * lg + r] = f2bf(oacc[nn][r] * linv);
    __syncthreads();
    const int q_ = lane >> 2, d0 = (lane & 3) << 4;
    const u16* orow = smem + w * (16 * 72) + q_ * 72 + d0;
    u16x8 o0 = *(const u16x8*)(orow);
    u16x8 o1 = *(const u16x8*)(orow + 8);
    size_t gaddr = ((size_t)bb * 2048 + q0 + w * 16 + q_) * 1024 + h * 64 + d0;
    *(u16x8*)(ao + gaddr) = o0;
    *(u16x8*)(ao + gaddr + 8) = o1;
}

// ---------------------------------------------------------------- launch
extern "C" void kernel_launch(void* const* d_in, const int* in_sizes, int n_in,
                              void* d_out, int out_size, void* d_ws, size_t ws_size,
                              hipStream_t stream) {
    const float* x  = (const float*)d_in[0];
    const float* Wq = (const float*)d_in[1];
    const float* bq = (const float*)d_in[2];
    const float* Wk = (const float*)d_in[3];
    const float* bk = (const float*)d_in[4];
    const float* Wv = (const float*)d_in[5];
    const float* bv = (const float*)d_in[6];
    const float* Wo = (const float*)d_in[7];
    const float* bo = (const float*)d_in[8];

    const size_t MB = 1u << 20;
    if (ws_size < 40 * MB) return;
    char* ws = (char*)d_ws;
    u16* xb    = (u16*)(ws);             // 8MB  [4096][1024] bf16 (reused as ao)
    u16* wqkvt = (u16*)(ws + 8 * MB);    // 6MB  [3072][1024] = [Wq^T;Wk^T;Wv^T]
    u16* wot   = (u16*)(ws + 14 * MB);   // 2MB  Wo^T
    u16* qb    = (u16*)(ws + 16 * MB);   // 8MB  [32][2048][64]
    u16* kb    = (u16*)(ws + 24 * MB);   // 8MB  [32][2048][64]
    u16* vt    = (u16*)(ws + 32 * MB);   // 8MB  [32][64][2048]
    u16* ao    = xb;

    cvt_x_k<<<2048, 256, 0, stream>>>(x, xb);
    cvt_wT_k<<<dim3(16, 16), 256, 0, stream>>>(Wq, wqkvt);
    cvt_wT_k<<<dim3(16, 16), 256, 0, stream>>>(Wk, wqkvt + (1u << 20));
    cvt_wT_k<<<dim3(16, 16), 256, 0, stream>>>(Wv, wqkvt + (2u << 20));
    cvt_wT_k<<<dim3(16, 16), 256, 0, stream>>>(Wo, wot);

    gemm_k<0><<<dim3(32, 24), 256, 0, stream>>>(xb, wqkvt, bq, bk, bv,
                                                qb, kb, vt, nullptr);
    attn_k<<<dim3(32, 32), 256, 0, stream>>>(qb, kb, vt, ao);
    gemm_k<1><<<dim3(32, 8), 256, 0, stream>>>(ao, wot, bo, nullptr, nullptr,
                                               nullptr, nullptr, nullptr,
                                               (float*)d_out);
}

// Round 5
// 175.839 us; speedup vs baseline: 1.3078x; 1.0961x over previous
//
#include <hip/hip_runtime.h>
#include <cstdint>
#include <cstddef>

typedef unsigned short u16;
typedef unsigned int u32;
typedef __bf16 bf16x8 __attribute__((ext_vector_type(8)));
typedef float f32x4 __attribute__((ext_vector_type(4)));
typedef u32 u32x4 __attribute__((ext_vector_type(4)));
typedef u32 u32x2 __attribute__((ext_vector_type(2)));
typedef unsigned short u16x8 __attribute__((ext_vector_type(8)));
typedef short s16x4 __attribute__((ext_vector_type(4)));

#if __has_builtin(__builtin_amdgcn_mfma_f32_16x16x16bf16_1k)
#define HAVE_MFMA16 1
#else
#define HAVE_MFMA16 0
#endif

// f32 -> bf16 round-to-nearest-even (finite inputs only)
__device__ __forceinline__ u16 f2bf(float f) {
    u32 u = __float_as_uint(f);
    u += 0x7fffu + ((u >> 16) & 1u);
    return (u16)(u >> 16);
}

// async global->LDS, 16B per lane. LDS ptr must be wave-uniform; HW adds lane*16.
__device__ __forceinline__ void gl16(const void* g, void* l) {
    __builtin_amdgcn_global_load_lds(
        (const __attribute__((address_space(1))) unsigned int*)g,
        (__attribute__((address_space(3))) unsigned int*)l, 16, 0, 0);
}

// ---------------------------------------------------------------- conversions
__global__ __launch_bounds__(256) void cvt_x_k(const float* __restrict__ x,
                                               u16* __restrict__ o) {
    int i = blockIdx.x * 256 + threadIdx.x;
    const float4* xv = (const float4*)x;
    float4 a = xv[2 * i], b = xv[2 * i + 1];
    ushort4 r0, r1;
    r0.x = f2bf(a.x); r0.y = f2bf(a.y); r0.z = f2bf(a.z); r0.w = f2bf(a.w);
    r1.x = f2bf(b.x); r1.y = f2bf(b.y); r1.z = f2bf(b.z); r1.w = f2bf(b.w);
    ((ushort4*)o)[2 * i] = r0;
    ((ushort4*)o)[2 * i + 1] = r1;
}

// W [1024][1024] f32 row-major (k,n) -> out [1024][1024] bf16 (n,k)  (i.e. W^T)
__global__ __launch_bounds__(256) void cvt_wT_k(const float* __restrict__ W,
                                                u16* __restrict__ o) {
    __shared__ float tile[64][65];
    const int bx = blockIdx.x, by = blockIdx.y;
    const int t = threadIdx.x, tn = t & 63, tr = t >> 6;
#pragma unroll
    for (int r = 0; r < 16; ++r) {
        int kk = r * 4 + tr;
        tile[kk][tn] = W[(size_t)(by * 64 + kk) * 1024 + bx * 64 + tn];
    }
    __syncthreads();
#pragma unroll
    for (int r = 0; r < 16; ++r) {
        int nn = r * 4 + tr;
        o[(size_t)(bx * 64 + nn) * 1024 + by * 64 + tn] = f2bf(tile[tn][nn]);
    }
}

// ---------------------------------------------------------------- GEMM 128x128
// A [M][1024] bf16 row-major, Bt [N][1024] bf16 (= B^T), K=1024.
// MODE 0: fused QKV epilogue -> q (pre-scaled by 0.125*log2e), k as
//         [BH][2048][64], v transposed [BH][64][2048]
// MODE 1: f32 out [M][1024] + bias
template <int MODE>
__global__ __launch_bounds__(256) void gemm_k(
    const u16* __restrict__ A, const u16* __restrict__ Bt,
    const float* __restrict__ bias0, const float* __restrict__ bias1,
    const float* __restrict__ bias2,
    u16* __restrict__ oq, u16* __restrict__ ok_, u16* __restrict__ ov,
    float* __restrict__ oc) {
    __shared__ __align__(16) u16 As[128 * 32];
    __shared__ __align__(16) u16 Bs[128 * 32];
    const int t = threadIdx.x, w = t >> 6, lane = t & 63;
    const int lr = lane & 15, lg = lane >> 4;
    const int brow = blockIdx.x * 128, bcol = blockIdx.y * 128;
    const int wr = w >> 1, wc = w & 1;
    const char* Ab = (const char*)A + (size_t)brow * 2048;
    const char* Bb = (const char*)Bt + (size_t)bcol * 2048;
    char* AsB = (char*)As;
    char* BsB = (char*)Bs;
    const int lrow = lane >> 2, lcol = (lane & 3) << 4;
    f32x4 acc[4][4];
#pragma unroll
    for (int m = 0; m < 4; ++m)
#pragma unroll
        for (int n = 0; n < 4; ++n) acc[m][n] = (f32x4){0.f, 0.f, 0.f, 0.f};

    for (int k0 = 0; k0 < 1024; k0 += 32) {
#pragma unroll
        for (int i = 0; i < 2; ++i) {
            int r0 = w * 32 + i * 16;
            gl16(Ab + (size_t)(r0 + lrow) * 2048 + k0 * 2 + lcol, AsB + r0 * 64);
            gl16(Bb + (size_t)(r0 + lrow) * 2048 + k0 * 2 + lcol, BsB + r0 * 64);
        }
        __syncthreads();
        bf16x8 af[4], bfr[4];
#pragma unroll
        for (int m = 0; m < 4; ++m)
            af[m] = *(const bf16x8*)(AsB + (wr * 64 + m * 16 + lr) * 64 + lg * 16);
#pragma unroll
        for (int n = 0; n < 4; ++n)
            bfr[n] = *(const bf16x8*)(BsB + (wc * 64 + n * 16 + lr) * 64 + lg * 16);
#pragma unroll
        for (int m = 0; m < 4; ++m)
#pragma unroll
            for (int n = 0; n < 4; ++n)
                acc[m][n] = __builtin_amdgcn_mfma_f32_16x16x32_bf16(af[m], bfr[n],
                                                                    acc[m][n], 0, 0, 0);
        __syncthreads();
    }

    const float QSCALE = 0.125f * 1.44269504f;
#pragma unroll
    for (int n = 0; n < 4; ++n) {
        const int col = bcol + wc * 64 + n * 16 + lr;
        if (MODE == 0) {
#pragma unroll
            for (int m = 0; m < 4; ++m)
#pragma unroll
                for (int r = 0; r < 4; ++r) {
                    int row = brow + wr * 64 + m * 16 + 4 * lg + r;
                    int b = row >> 11, l = row & 2047;
                    float val = acc[m][n][r];
                    if (col < 1024) {
                        int hh = col >> 6, d = col & 63;
                        oq[(((size_t)b * 16 + hh) * 2048 + l) * 64 + d] =
                            f2bf((val + bias0[col]) * QSCALE);
                    } else if (col < 2048) {
                        int c = col - 1024, hh = c >> 6, d = c & 63;
                        ok_[(((size_t)b * 16 + hh) * 2048 + l) * 64 + d] =
                            f2bf(val + bias1[c]);
                    } else {
                        int c = col - 2048, hh = c >> 6, d = c & 63;
                        ov[(((size_t)b * 16 + hh) * 64 + d) * 2048 + l] =
                            f2bf(val + bias2[c]);
                    }
                }
        } else {
            const float bb = bias0[col];
#pragma unroll
            for (int m = 0; m < 4; ++m)
#pragma unroll
                for (int r = 0; r < 4; ++r) {
                    int row = brow + wr * 64 + m * 16 + 4 * lg + r;
                    oc[(size_t)row * 1024 + col] = acc[m][n][r] + bb;
                }
        }
    }
}

// ---------------------------------------------------------------- attention
// q (pre-scaled by 0.125*log2e), k: [BH][2048][64] bf16; vt: [BH][64][2048]
// ao: [B*2048][1024] bf16
// S^T = mfma(K,Q). MAX-FREE softmax: exponent e = S' + sl2*(j-2047) - 16 + 0,
// where sl2*(jloc-2047)-16 rides in the MFMA C-init (iter-invariant) and
// sl2*j0 is a per-tile uniform scalar add. No running max, no rescale.
// PV: 16x16x16 MFMA whose B-frag layout == S^T C-layout (no P exchange).
__global__ __launch_bounds__(256, 4) void attn_k(const u16* __restrict__ qg_,
                                                 const u16* __restrict__ kg_,
                                                 const u16* __restrict__ vg_,
                                                 u16* __restrict__ ao) {
    __shared__ __align__(16) u16 smem[16384];   // 32KB: K0|K1|V0|V1 (8KB each)
    char* base = (char*)smem;
    const int t = threadIdx.x, w = t >> 6, lane = t & 63;
    const int lr = lane & 15, lg = lane >> 4;
    // XCD swizzle: blocks sharing bh land on one XCD (bid%8 groups)
    const int bid = blockIdx.y * 32 + blockIdx.x;
    const int qt = (bid >> 3) & 31;
    const int bh = ((bid >> 8) << 3) | (bid & 7);
    const int q0 = qt * 64, h = bh & 15, bb = bh >> 4;
    const float sl2 = exp2f(-0.5f * (float)(h + 1)) * 1.44269504f; // slope*log2e

    // staging offsets (XOR-swizzled source, linear LDS dest); wave w stages
    // rows w*16..w*16+15 of each 64-row tile (128B rows)
    const int U0 = (w * 2) * 64 + lane, U1 = U0 + 64;
    const int rr0 = U0 >> 3, u0 = U0 & 7, rr1 = U1 >> 3, u1 = U1 & 7;
    const int koff0 = rr0 * 128 + ((u0 ^ (rr0 & 7)) << 4);
    const int koff1 = rr1 * 128 + ((u1 ^ (rr1 & 7)) << 4);
    const int voff0 = rr0 * 4096 + ((u0 ^ (rr0 & 7)) << 4);
    const int voff1 = rr1 * 4096 + ((u1 ^ (rr1 & 7)) << 4);
    const int lds0 = (w * 2) * 1024, lds1 = lds0 + 1024;

    const char* khead = (const char*)(kg_ + (size_t)bh * 2048 * 64);
    const char* vhead = (const char*)(vg_ + (size_t)bh * 64 * 2048);

    // stage tile 0
    gl16(khead + koff0, base + lds0);
    gl16(khead + koff1, base + lds1);
    gl16(vhead + voff0, base + 16384 + lds0);
    gl16(vhead + voff1, base + 16384 + lds1);

    // Q fragments straight from global (B-operand of 16x16x32 QK^T)
    const char* qp = (const char*)qg_ +
                     ((size_t)bh * 2048 + q0 + w * 16 + lr) * 128;
    bf16x8 qa0 = *(const bf16x8*)(qp + lg * 16);
    bf16x8 qa1 = *(const bf16x8*)(qp + 64 + lg * 16);

    // C-init: abF2[n][r] = sl2*(jloc - 2047) - 16, jloc = n*16 + 4lg + r
    f32x4 abF2[4];
#pragma unroll
    for (int n = 0; n < 4; ++n)
#pragma unroll
        for (int r = 0; r < 4; ++r)
            abF2[n][r] = sl2 * (float)(n * 16 + 4 * lg + r - 2047) - 16.0f;
    const float ainc = sl2 * 64.0f;
    float scalJ = 0.f;                // sl2 * j0
    f32x4 oacc[4], l4;
#pragma unroll
    for (int nn = 0; nn < 4; ++nn) oacc[nn] = (f32x4){0.f, 0.f, 0.f, 0.f};
    l4 = (f32x4){0.f, 0.f, 0.f, 0.f};
#if !HAVE_MFMA16
    const int srcA = lr + ((lg & 1) << 5);
    const int srcB = srcA + 16;
    const bool hiHalf = (lg >> 1) != 0;
#endif

    asm volatile("s_waitcnt vmcnt(0)" ::: "memory");
    __builtin_amdgcn_s_barrier();
    __builtin_amdgcn_sched_barrier(0);

    for (int tt = 0; tt < 32; ++tt) {
        const char* Kc = base + (tt & 1) * 8192;
        const char* Vc = base + 16384 + (tt & 1) * 8192;
        if (tt < 31) {   // stage next tile into the other buffer
            const char* ks = khead + (size_t)(tt + 1) * 8192;
            const char* vs = vhead + (size_t)(tt + 1) * 128;
            char* Kn = base + ((tt + 1) & 1) * 8192;
            char* Vn = base + 16384 + ((tt + 1) & 1) * 8192;
            gl16(ks + koff0, Kn + lds0);
            gl16(ks + koff1, Kn + lds1);
            gl16(vs + voff0, Vn + lds0);
            gl16(vs + voff1, Vn + lds1);
        }

        // S^T = mfma(K, Q) + bias C-init: lane has e' = S'[j][q=lr] + abF2
        f32x4 sa[4];
        __builtin_amdgcn_s_setprio(1);
#pragma unroll
        for (int n = 0; n < 4; ++n) {
            bf16x8 kf = *(const bf16x8*)(Kc + (n * 16 + lr) * 128 +
                                         ((lg ^ (lr & 7)) << 4));
            sa[n] = __builtin_amdgcn_mfma_f32_16x16x32_bf16(kf, qa0, abF2[n],
                                                            0, 0, 0);
        }
#pragma unroll
        for (int n = 0; n < 4; ++n) {
            bf16x8 kf = *(const bf16x8*)(Kc + (n * 16 + lr) * 128 +
                                         (((4 + lg) ^ (lr & 7)) << 4));
            sa[n] = __builtin_amdgcn_mfma_f32_16x16x32_bf16(kf, qa1, sa[n],
                                                            0, 0, 0);
        }
        __builtin_amdgcn_s_setprio(0);

        // max-free softmax: P = exp2(e' + sl2*j0); sums deferred to epilogue
#pragma unroll
        for (int n = 0; n < 4; ++n)
#pragma unroll
            for (int r = 0; r < 4; ++r)
                sa[n][r] = exp2f(sa[n][r] + scalJ);
#pragma unroll
        for (int n = 0; n < 4; ++n) l4 += sa[n];
        scalJ += ainc;

#if HAVE_MFMA16
        // pack P (C-layout) into 16x16x16 B-frags: col=q=lr, k=4lg+e == j-layout
        s16x4 pn[4];
#pragma unroll
        for (int n = 0; n < 4; ++n) {
            u32 lo, hi;
            asm("v_cvt_pk_bf16_f32 %0, %1, %2"
                : "=v"(lo) : "v"(sa[n][0]), "v"(sa[n][1]));
            asm("v_cvt_pk_bf16_f32 %0, %1, %2"
                : "=v"(hi) : "v"(sa[n][2]), "v"(sa[n][3]));
            u32x2 tmp = {lo, hi};
            pn[n] = __builtin_bit_cast(s16x4, tmp);
        }
        // O^T += V^T * P per 16-j slice: A-frag = V^T row nn*16+lr, k=4lg+e
        __builtin_amdgcn_s_setprio(1);
#pragma unroll
        for (int n = 0; n < 4; ++n)
#pragma unroll
            for (int nn = 0; nn < 4; ++nn) {
                s16x4 va = *(const s16x4*)(Vc + (nn * 16 + lr) * 128 +
                                           (((2 * n + (lg >> 1)) ^ (lr & 7)) << 4) +
                                           ((lg & 1) << 3));
                oacc[nn] = __builtin_amdgcn_mfma_f32_16x16x16bf16_1k(va, pn[n],
                                                                     oacc[nn],
                                                                     0, 0, 0);
            }
        __builtin_amdgcn_s_setprio(0);
#else
        // fallback: exchange to 16x16x32 B-frag layout (R4-proven path)
        u32 pk[8];
#pragma unroll
        for (int n = 0; n < 4; ++n)
#pragma unroll
            for (int rp = 0; rp < 2; ++rp) {
                u32 rpk;
                asm("v_cvt_pk_bf16_f32 %0, %1, %2"
                    : "=v"(rpk) : "v"(sa[n][2 * rp]), "v"(sa[n][2 * rp + 1]));
                pk[n * 2 + rp] = rpk;
            }
        u32x4 pb0, pb1;
#pragma unroll
        for (int g = 0; g < 4; ++g) {
            int src = (g < 2) ? srcA : srcB;
            u32 a0 = (u32)__shfl((int)pk[0 + (g & 1)], src);
            u32 a1 = (u32)__shfl((int)pk[2 + (g & 1)], src);
            u32 b0 = (u32)__shfl((int)pk[4 + (g & 1)], src);
            u32 b1 = (u32)__shfl((int)pk[6 + (g & 1)], src);
            pb0[g] = hiHalf ? a1 : a0;
            pb1[g] = hiHalf ? b1 : b0;
        }
        bf16x8 pf0 = __builtin_bit_cast(bf16x8, pb0);
        bf16x8 pf1 = __builtin_bit_cast(bf16x8, pb1);
        __builtin_amdgcn_s_setprio(1);
#pragma unroll
        for (int nn = 0; nn < 4; ++nn) {
            bf16x8 vf0 = *(const bf16x8*)(Vc + (nn * 16 + lr) * 128 +
                                          ((lg ^ (lr & 7)) << 4));
            oacc[nn] = __builtin_amdgcn_mfma_f32_16x16x32_bf16(vf0, pf0, oacc[nn],
                                                               0, 0, 0);
            bf16x8 vf1 = *(const bf16x8*)(Vc + (nn * 16 + lr) * 128 +
                                          (((4 + lg) ^ (lr & 7)) << 4));
            oacc[nn] = __builtin_amdgcn_mfma_f32_16x16x32_bf16(vf1, pf1, oacc[nn],
                                                               0, 0, 0);
        }
        __builtin_amdgcn_s_setprio(0);
#endif

        // drain next-tile staging (issued before compute -> latency hidden)
        asm volatile("s_waitcnt vmcnt(0)" ::: "memory");
        __builtin_amdgcn_s_barrier();
        __builtin_amdgcn_sched_barrier(0);
    }

    // epilogue: l reduction, normalize, transpose O^T -> O via LDS
    float l = (l4[0] + l4[1]) + (l4[2] + l4[3]);
    l += __shfl_xor(l, 16);
    l += __shfl_xor(l, 32);
    const float linv = 1.0f / l;
    u16* ow = smem + w * (16 * 72);
#pragma unroll
    for (int nn = 0; nn < 4; ++nn)
#pragma unroll
        for (int r = 0; r < 4; ++r)
            ow[lr * 72 + nn * 16 + 4 * lg + r] = f2bf(oacc[nn][r] * linv);
    __syncthreads();
    const int q_ = lane >> 2, d0 = (lane & 3) << 4;
    const u16* orow = smem + w * (16 * 72) + q_ * 72 + d0;
    u16x8 o0 = *(const u16x8*)(orow);
    u16x8 o1 = *(const u16x8*)(orow + 8);
    size_t gaddr = ((size_t)bb * 2048 + q0 + w * 16 + q_) * 1024 + h * 64 + d0;
    *(u16x8*)(ao + gaddr) = o0;
    *(u16x8*)(ao + gaddr + 8) = o1;
}

// ---------------------------------------------------------------- launch
extern "C" void kernel_launch(void* const* d_in, const int* in_sizes, int n_in,
                              void* d_out, int out_size, void* d_ws, size_t ws_size,
                              hipStream_t stream) {
    const float* x  = (const float*)d_in[0];
    const float* Wq = (const float*)d_in[1];
    const float* bq = (const float*)d_in[2];
    const float* Wk = (const float*)d_in[3];
    const float* bk = (const float*)d_in[4];
    const float* Wv = (const float*)d_in[5];
    const float* bv = (const float*)d_in[6];
    const float* Wo = (const float*)d_in[7];
    const float* bo = (const float*)d_in[8];

    const size_t MB = 1u << 20;
    if (ws_size < 40 * MB) return;
    char* ws = (char*)d_ws;
    u16* xb    = (u16*)(ws);             // 8MB  [4096][1024] bf16 (reused as ao)
    u16* wqkvt = (u16*)(ws + 8 * MB);    // 6MB  [3072][1024] = [Wq^T;Wk^T;Wv^T]
    u16* wot   = (u16*)(ws + 14 * MB);   // 2MB  Wo^T
    u16* qb    = (u16*)(ws + 16 * MB);   // 8MB  [32][2048][64]
    u16* kb    = (u16*)(ws + 24 * MB);   // 8MB  [32][2048][64]
    u16* vt    = (u16*)(ws + 32 * MB);   // 8MB  [32][64][2048]
    u16* ao    = xb;

    cvt_x_k<<<2048, 256, 0, stream>>>(x, xb);
    cvt_wT_k<<<dim3(16, 16), 256, 0, stream>>>(Wq, wqkvt);
    cvt_wT_k<<<dim3(16, 16), 256, 0, stream>>>(Wk, wqkvt + (1u << 20));
    cvt_wT_k<<<dim3(16, 16), 256, 0, stream>>>(Wv, wqkvt + (2u << 20));
    cvt_wT_k<<<dim3(16, 16), 256, 0, stream>>>(Wo, wot);

    gemm_k<0><<<dim3(32, 24), 256, 0, stream>>>(xb, wqkvt, bq, bk, bv,
                                                qb, kb, vt, nullptr);
    attn_k<<<dim3(32, 32), 256, 0, stream>>>(qb, kb, vt, ao);
    gemm_k<1><<<dim3(32, 8), 256, 0, stream>>>(ao, wot, bo, nullptr, nullptr,
                                               nullptr, nullptr, nullptr,
                                               (float*)d_out);
}

// Round 6
// 159.278 us; speedup vs baseline: 1.4438x; 1.1040x over previous
//
#include <hip/hip_runtime.h>
#include <cstdint>
#include <cstddef>

typedef unsigned short u16;
typedef unsigned int u32;
typedef __bf16 bf16x8 __attribute__((ext_vector_type(8)));
typedef float f32x4 __attribute__((ext_vector_type(4)));
typedef u32 u32x4 __attribute__((ext_vector_type(4)));
typedef u32 u32x2 __attribute__((ext_vector_type(2)));
typedef unsigned short u16x8 __attribute__((ext_vector_type(8)));
typedef short s16x4 __attribute__((ext_vector_type(4)));

#if __has_builtin(__builtin_amdgcn_mfma_f32_16x16x16bf16_1k)
#define HAVE_MFMA16 1
#else
#define HAVE_MFMA16 0
#endif

// f32 -> bf16 round-to-nearest-even (finite inputs only)
__device__ __forceinline__ u16 f2bf(float f) {
    u32 u = __float_as_uint(f);
    u += 0x7fffu + ((u >> 16) & 1u);
    return (u16)(u >> 16);
}

// async global->LDS, 16B per lane. LDS ptr must be wave-uniform; HW adds lane*16.
__device__ __forceinline__ void gl16(const void* g, void* l) {
    __builtin_amdgcn_global_load_lds(
        (const __attribute__((address_space(1))) unsigned int*)g,
        (__attribute__((address_space(3))) unsigned int*)l, 16, 0, 0);
}

// ---------------------------------------------------------------- conversions
__global__ __launch_bounds__(256) void cvt_x_k(const float* __restrict__ x,
                                               u16* __restrict__ o) {
    int i = blockIdx.x * 256 + threadIdx.x;
    const float4* xv = (const float4*)x;
    float4 a = xv[2 * i], b = xv[2 * i + 1];
    ushort4 r0, r1;
    r0.x = f2bf(a.x); r0.y = f2bf(a.y); r0.z = f2bf(a.z); r0.w = f2bf(a.w);
    r1.x = f2bf(b.x); r1.y = f2bf(b.y); r1.z = f2bf(b.z); r1.w = f2bf(b.w);
    ((ushort4*)o)[2 * i] = r0;
    ((ushort4*)o)[2 * i + 1] = r1;
}

// W [1024][1024] f32 row-major (k,n) -> out [1024][1024] bf16 (n,k)  (i.e. W^T)
__global__ __launch_bounds__(256) void cvt_wT_k(const float* __restrict__ W,
                                                u16* __restrict__ o) {
    __shared__ float tile[64][65];
    const int bx = blockIdx.x, by = blockIdx.y;
    const int t = threadIdx.x, tn = t & 63, tr = t >> 6;
#pragma unroll
    for (int r = 0; r < 16; ++r) {
        int kk = r * 4 + tr;
        tile[kk][tn] = W[(size_t)(by * 64 + kk) * 1024 + bx * 64 + tn];
    }
    __syncthreads();
#pragma unroll
    for (int r = 0; r < 16; ++r) {
        int nn = r * 4 + tr;
        o[(size_t)(bx * 64 + nn) * 1024 + by * 64 + tn] = f2bf(tile[tn][nn]);
    }
}

// ---------------------------------------------------------------- GEMM 128x128
// A [M][1024] bf16 row-major, Bt [N][1024] bf16 (= B^T), K=1024.
// 2-phase double-buffered: stage(t+1) || compute(t); one vmcnt(0)+barrier/iter.
// MODE 0: fused QKV epilogue -> q (pre-scaled by 0.125*log2e), k as
//         [BH][2048][64], v transposed [BH][64][2048]
// MODE 1: f32 out [M][1024] + bias
template <int MODE>
__global__ __launch_bounds__(256) void gemm_k(
    const u16* __restrict__ A, const u16* __restrict__ Bt,
    const float* __restrict__ bias0, const float* __restrict__ bias1,
    const float* __restrict__ bias2,
    u16* __restrict__ oq, u16* __restrict__ ok_, u16* __restrict__ ov,
    float* __restrict__ oc) {
    __shared__ __align__(16) u16 As[2][128 * 32];
    __shared__ __align__(16) u16 Bs[2][128 * 32];
    const int t = threadIdx.x, w = t >> 6, lane = t & 63;
    const int lr = lane & 15, lg = lane >> 4;
    const int brow = blockIdx.x * 128, bcol = blockIdx.y * 128;
    const int wr = w >> 1, wc = w & 1;
    const char* Ab = (const char*)A + (size_t)brow * 2048;
    const char* Bb = (const char*)Bt + (size_t)bcol * 2048;
    const int lrow = lane >> 2, lcol = (lane & 3) << 4;
    // per-wave staging rows (16 rows x 64B per gl16 instruction)
    const int r0a = w * 32, r0b = w * 32 + 16;
    const size_t ga = (size_t)(r0a + lrow) * 2048 + lcol;
    const size_t gb = (size_t)(r0b + lrow) * 2048 + lcol;

    f32x4 acc[4][4];
#pragma unroll
    for (int m = 0; m < 4; ++m)
#pragma unroll
        for (int n = 0; n < 4; ++n) acc[m][n] = (f32x4){0.f, 0.f, 0.f, 0.f};

    // prologue: stage K-step 0 into buffer 0
    gl16(Ab + ga, (char*)As[0] + r0a * 64);
    gl16(Ab + gb, (char*)As[0] + r0b * 64);
    gl16(Bb + ga, (char*)Bs[0] + r0a * 64);
    gl16(Bb + gb, (char*)Bs[0] + r0b * 64);
    asm volatile("s_waitcnt vmcnt(0)" ::: "memory");
    __builtin_amdgcn_s_barrier();
    __builtin_amdgcn_sched_barrier(0);

    for (int tt = 0; tt < 32; ++tt) {
        const char* AsB = (const char*)As[tt & 1];
        const char* BsB = (const char*)Bs[tt & 1];
        if (tt < 31) {   // stage next K-step into the other buffer
            const int nb = (tt + 1) & 1;
            const size_t ko = (size_t)(tt + 1) * 64;   // 32 elems * 2B
            gl16(Ab + ga + ko, (char*)As[nb] + r0a * 64);
            gl16(Ab + gb + ko, (char*)As[nb] + r0b * 64);
            gl16(Bb + ga + ko, (char*)Bs[nb] + r0a * 64);
            gl16(Bb + gb + ko, (char*)Bs[nb] + r0b * 64);
        }
        bf16x8 af[4], bfr[4];
#pragma unroll
        for (int m = 0; m < 4; ++m)
            af[m] = *(const bf16x8*)(AsB + (wr * 64 + m * 16 + lr) * 64 + lg * 16);
#pragma unroll
        for (int n = 0; n < 4; ++n)
            bfr[n] = *(const bf16x8*)(BsB + (wc * 64 + n * 16 + lr) * 64 + lg * 16);
#pragma unroll
        for (int m = 0; m < 4; ++m)
#pragma unroll
            for (int n = 0; n < 4; ++n)
                acc[m][n] = __builtin_amdgcn_mfma_f32_16x16x32_bf16(af[m], bfr[n],
                                                                    acc[m][n], 0, 0, 0);
        // drain next-tile staging (hidden under the MFMAs above), then sync
        asm volatile("s_waitcnt vmcnt(0)" ::: "memory");
        __builtin_amdgcn_s_barrier();
        __builtin_amdgcn_sched_barrier(0);
    }

    const float QSCALE = 0.125f * 1.44269504f;
#pragma unroll
    for (int n = 0; n < 4; ++n) {
        const int col = bcol + wc * 64 + n * 16 + lr;
        if (MODE == 0) {
#pragma unroll
            for (int m = 0; m < 4; ++m)
#pragma unroll
                for (int r = 0; r < 4; ++r) {
                    int row = brow + wr * 64 + m * 16 + 4 * lg + r;
                    int b = row >> 11, l = row & 2047;
                    float val = acc[m][n][r];
                    if (col < 1024) {
                        int hh = col >> 6, d = col & 63;
                        oq[(((size_t)b * 16 + hh) * 2048 + l) * 64 + d] =
                            f2bf((val + bias0[col]) * QSCALE);
                    } else if (col < 2048) {
                        int c = col - 1024, hh = c >> 6, d = c & 63;
                        ok_[(((size_t)b * 16 + hh) * 2048 + l) * 64 + d] =
                            f2bf(val + bias1[c]);
                    } else {
                        int c = col - 2048, hh = c >> 6, d = c & 63;
                        ov[(((size_t)b * 16 + hh) * 64 + d) * 2048 + l] =
                            f2bf(val + bias2[c]);
                    }
                }
        } else {
            const float bb = bias0[col];
#pragma unroll
            for (int m = 0; m < 4; ++m)
#pragma unroll
                for (int r = 0; r < 4; ++r) {
                    int row = brow + wr * 64 + m * 16 + 4 * lg + r;
                    oc[(size_t)row * 1024 + col] = acc[m][n][r] + bb;
                }
        }
    }
}

// ---------------------------------------------------------------- attention
// q (pre-scaled by 0.125*log2e), k: [BH][2048][64] bf16; vt: [BH][64][2048]
// ao: [B*2048][1024] bf16
// S^T = mfma(K,Q). MAX-FREE softmax: exponent e = S' + sl2*(j-2047) - 16 + 0,
// where sl2*(jloc-2047)-16 rides in the MFMA C-init (iter-invariant) and
// sl2*j0 is a per-tile uniform scalar add. No running max, no rescale.
// PV: 16x16x16 MFMA whose B-frag layout == S^T C-layout (no P exchange).
__global__ __launch_bounds__(256, 4) void attn_k(const u16* __restrict__ qg_,
                                                 const u16* __restrict__ kg_,
                                                 const u16* __restrict__ vg_,
                                                 u16* __restrict__ ao) {
    __shared__ __align__(16) u16 smem[16384];   // 32KB: K0|K1|V0|V1 (8KB each)
    char* base = (char*)smem;
    const int t = threadIdx.x, w = t >> 6, lane = t & 63;
    const int lr = lane & 15, lg = lane >> 4;
    // XCD swizzle: blocks sharing bh land on one XCD (bid%8 groups)
    const int bid = blockIdx.y * 32 + blockIdx.x;
    const int qt = (bid >> 3) & 31;
    const int bh = ((bid >> 8) << 3) | (bid & 7);
    const int q0 = qt * 64, h = bh & 15, bb = bh >> 4;
    const float sl2 = exp2f(-0.5f * (float)(h + 1)) * 1.44269504f; // slope*log2e

    // staging offsets (XOR-swizzled source, linear LDS dest); wave w stages
    // rows w*16..w*16+15 of each 64-row tile (128B rows)
    const int U0 = (w * 2) * 64 + lane, U1 = U0 + 64;
    const int rr0 = U0 >> 3, u0 = U0 & 7, rr1 = U1 >> 3, u1 = U1 & 7;
    const int koff0 = rr0 * 128 + ((u0 ^ (rr0 & 7)) << 4);
    const int koff1 = rr1 * 128 + ((u1 ^ (rr1 & 7)) << 4);
    const int voff0 = rr0 * 4096 + ((u0 ^ (rr0 & 7)) << 4);
    const int voff1 = rr1 * 4096 + ((u1 ^ (rr1 & 7)) << 4);
    const int lds0 = (w * 2) * 1024, lds1 = lds0 + 1024;

    const char* khead = (const char*)(kg_ + (size_t)bh * 2048 * 64);
    const char* vhead = (const char*)(vg_ + (size_t)bh * 64 * 2048);

    // stage tile 0
    gl16(khead + koff0, base + lds0);
    gl16(khead + koff1, base + lds1);
    gl16(vhead + voff0, base + 16384 + lds0);
    gl16(vhead + voff1, base + 16384 + lds1);

    // Q fragments straight from global (B-operand of 16x16x32 QK^T)
    const char* qp = (const char*)qg_ +
                     ((size_t)bh * 2048 + q0 + w * 16 + lr) * 128;
    bf16x8 qa0 = *(const bf16x8*)(qp + lg * 16);
    bf16x8 qa1 = *(const bf16x8*)(qp + 64 + lg * 16);

    // C-init: abF2[n][r] = sl2*(jloc - 2047) - 16, jloc = n*16 + 4lg + r
    f32x4 abF2[4];
#pragma unroll
    for (int n = 0; n < 4; ++n)
#pragma unroll
        for (int r = 0; r < 4; ++r)
            abF2[n][r] = sl2 * (float)(n * 16 + 4 * lg + r - 2047) - 16.0f;
    const float ainc = sl2 * 64.0f;
    float scalJ = 0.f;                // sl2 * j0
    f32x4 oacc[4], l4;
#pragma unroll
    for (int nn = 0; nn < 4; ++nn) oacc[nn] = (f32x4){0.f, 0.f, 0.f, 0.f};
    l4 = (f32x4){0.f, 0.f, 0.f, 0.f};
#if !HAVE_MFMA16
    const int srcA = lr + ((lg & 1) << 5);
    const int srcB = srcA + 16;
    const bool hiHalf = (lg >> 1) != 0;
#endif

    asm volatile("s_waitcnt vmcnt(0)" ::: "memory");
    __builtin_amdgcn_s_barrier();
    __builtin_amdgcn_sched_barrier(0);

    for (int tt = 0; tt < 32; ++tt) {
        const char* Kc = base + (tt & 1) * 8192;
        const char* Vc = base + 16384 + (tt & 1) * 8192;
        if (tt < 31) {   // stage next tile into the other buffer
            const char* ks = khead + (size_t)(tt + 1) * 8192;
            const char* vs = vhead + (size_t)(tt + 1) * 128;
            char* Kn = base + ((tt + 1) & 1) * 8192;
            char* Vn = base + 16384 + ((tt + 1) & 1) * 8192;
            gl16(ks + koff0, Kn + lds0);
            gl16(ks + koff1, Kn + lds1);
            gl16(vs + voff0, Vn + lds0);
            gl16(vs + voff1, Vn + lds1);
        }

        // S^T = mfma(K, Q) + bias C-init: lane has e' = S'[j][q=lr] + abF2
        f32x4 sa[4];
        __builtin_amdgcn_s_setprio(1);
#pragma unroll
        for (int n = 0; n < 4; ++n) {
            bf16x8 kf = *(const bf16x8*)(Kc + (n * 16 + lr) * 128 +
                                         ((lg ^ (lr & 7)) << 4));
            sa[n] = __builtin_amdgcn_mfma_f32_16x16x32_bf16(kf, qa0, abF2[n],
                                                            0, 0, 0);
        }
#pragma unroll
        for (int n = 0; n < 4; ++n) {
            bf16x8 kf = *(const bf16x8*)(Kc + (n * 16 + lr) * 128 +
                                         (((4 + lg) ^ (lr & 7)) << 4));
            sa[n] = __builtin_amdgcn_mfma_f32_16x16x32_bf16(kf, qa1, sa[n],
                                                            0, 0, 0);
        }
        __builtin_amdgcn_s_setprio(0);

        // max-free softmax: P = exp2(e' + sl2*j0); sums deferred to epilogue
#pragma unroll
        for (int n = 0; n < 4; ++n)
#pragma unroll
            for (int r = 0; r < 4; ++r)
                sa[n][r] = exp2f(sa[n][r] + scalJ);
#pragma unroll
        for (int n = 0; n < 4; ++n) l4 += sa[n];
        scalJ += ainc;

#if HAVE_MFMA16
        // pack P (C-layout) into 16x16x16 B-frags: col=q=lr, k=4lg+e == j-layout
        s16x4 pn[4];
#pragma unroll
        for (int n = 0; n < 4; ++n) {
            u32 lo, hi;
            asm("v_cvt_pk_bf16_f32 %0, %1, %2"
                : "=v"(lo) : "v"(sa[n][0]), "v"(sa[n][1]));
            asm("v_cvt_pk_bf16_f32 %0, %1, %2"
                : "=v"(hi) : "v"(sa[n][2]), "v"(sa[n][3]));
            u32x2 tmp = {lo, hi};
            pn[n] = __builtin_bit_cast(s16x4, tmp);
        }
        // O^T += V^T * P per 16-j slice: A-frag = V^T row nn*16+lr, k=4lg+e
        __builtin_amdgcn_s_setprio(1);
#pragma unroll
        for (int n = 0; n < 4; ++n)
#pragma unroll
            for (int nn = 0; nn < 4; ++nn) {
                s16x4 va = *(const s16x4*)(Vc + (nn * 16 + lr) * 128 +
                                           (((2 * n + (lg >> 1)) ^ (lr & 7)) << 4) +
                                           ((lg & 1) << 3));
                oacc[nn] = __builtin_amdgcn_mfma_f32_16x16x16bf16_1k(va, pn[n],
                                                                     oacc[nn],
                                                                     0, 0, 0);
            }
        __builtin_amdgcn_s_setprio(0);
#else
        // fallback: exchange to 16x16x32 B-frag layout (R4-proven path)
        u32 pk[8];
#pragma unroll
        for (int n = 0; n < 4; ++n)
#pragma unroll
            for (int rp = 0; rp < 2; ++rp) {
                u32 rpk;
                asm("v_cvt_pk_bf16_f32 %0, %1, %2"
                    : "=v"(rpk) : "v"(sa[n][2 * rp]), "v"(sa[n][2 * rp + 1]));
                pk[n * 2 + rp] = rpk;
            }
        u32x4 pb0, pb1;
#pragma unroll
        for (int g = 0; g < 4; ++g) {
            int src = (g < 2) ? srcA : srcB;
            u32 a0 = (u32)__shfl((int)pk[0 + (g & 1)], src);
            u32 a1 = (u32)__shfl((int)pk[2 + (g & 1)], src);
            u32 b0 = (u32)__shfl((int)pk[4 + (g & 1)], src);
            u32 b1 = (u32)__shfl((int)pk[6 + (g & 1)], src);
            pb0[g] = hiHalf ? a1 : a0;
            pb1[g] = hiHalf ? b1 : b0;
        }
        bf16x8 pf0 = __builtin_bit_cast(bf16x8, pb0);
        bf16x8 pf1 = __builtin_bit_cast(bf16x8, pb1);
        __builtin_amdgcn_s_setprio(1);
#pragma unroll
        for (int nn = 0; nn < 4; ++nn) {
            bf16x8 vf0 = *(const bf16x8*)(Vc + (nn * 16 + lr) * 128 +
                                          ((lg ^ (lr & 7)) << 4));
            oacc[nn] = __builtin_amdgcn_mfma_f32_16x16x32_bf16(vf0, pf0, oacc[nn],
                                                               0, 0, 0);
            bf16x8 vf1 = *(const bf16x8*)(Vc + (nn * 16 + lr) * 128 +
                                          (((4 + lg) ^ (lr & 7)) << 4));
            oacc[nn] = __builtin_amdgcn_mfma_f32_16x16x32_bf16(vf1, pf1, oacc[nn],
                                                               0, 0, 0);
        }
        __builtin_amdgcn_s_setprio(0);
#endif

        // drain next-tile staging (issued before compute -> latency hidden)
        asm volatile("s_waitcnt vmcnt(0)" ::: "memory");
        __builtin_amdgcn_s_barrier();
        __builtin_amdgcn_sched_barrier(0);
    }

    // epilogue: l reduction, normalize, transpose O^T -> O via LDS
    float l = (l4[0] + l4[1]) + (l4[2] + l4[3]);
    l += __shfl_xor(l, 16);
    l += __shfl_xor(l, 32);
    const float linv = 1.0f / l;
    u16* ow = smem + w * (16 * 72);
#pragma unroll
    for (int nn = 0; nn < 4; ++nn)
#pragma unroll
        for (int r = 0; r < 4; ++r)
            ow[lr * 72 + nn * 16 + 4 * lg + r] = f2bf(oacc[nn][r] * linv);
    __syncthreads();
    const int q_ = lane >> 2, d0 = (lane & 3) << 4;
    const u16* orow = smem + w * (16 * 72) + q_ * 72 + d0;
    u16x8 o0 = *(const u16x8*)(orow);
    u16x8 o1 = *(const u16x8*)(orow + 8);
    size_t gaddr = ((size_t)bb * 2048 + q0 + w * 16 + q_) * 1024 + h * 64 + d0;
    *(u16x8*)(ao + gaddr) = o0;
    *(u16x8*)(ao + gaddr + 8) = o1;
}

// ---------------------------------------------------------------- launch
extern "C" void kernel_launch(void* const* d_in, const int* in_sizes, int n_in,
                              void* d_out, int out_size, void* d_ws, size_t ws_size,
                              hipStream_t stream) {
    const float* x  = (const float*)d_in[0];
    const float* Wq = (const float*)d_in[1];
    const float* bq = (const float*)d_in[2];
    const float* Wk = (const float*)d_in[3];
    const float* bk = (const float*)d_in[4];
    const float* Wv = (const float*)d_in[5];
    const float* bv = (const float*)d_in[6];
    const float* Wo = (const float*)d_in[7];
    const float* bo = (const float*)d_in[8];

    const size_t MB = 1u << 20;
    if (ws_size < 40 * MB) return;
    char* ws = (char*)d_ws;
    u16* xb    = (u16*)(ws);             // 8MB  [4096][1024] bf16 (reused as ao)
    u16* wqkvt = (u16*)(ws + 8 * MB);    // 6MB  [3072][1024] = [Wq^T;Wk^T;Wv^T]
    u16* wot   = (u16*)(ws + 14 * MB);   // 2MB  Wo^T
    u16* qb    = (u16*)(ws + 16 * MB);   // 8MB  [32][2048][64]
    u16* kb    = (u16*)(ws + 24 * MB);   // 8MB  [32][2048][64]
    u16* vt    = (u16*)(ws + 32 * MB);   // 8MB  [32][64][2048]
    u16* ao    = xb;

    cvt_x_k<<<2048, 256, 0, stream>>>(x, xb);
    cvt_wT_k<<<dim3(16, 16), 256, 0, stream>>>(Wq, wqkvt);
    cvt_wT_k<<<dim3(16, 16), 256, 0, stream>>>(Wk, wqkvt + (1u << 20));
    cvt_wT_k<<<dim3(16, 16), 256, 0, stream>>>(Wv, wqkvt + (2u << 20));
    cvt_wT_k<<<dim3(16, 16), 256, 0, stream>>>(Wo, wot);

    gemm_k<0><<<dim3(32, 24), 256, 0, stream>>>(xb, wqkvt, bq, bk, bv,
                                                qb, kb, vt, nullptr);
    attn_k<<<dim3(32, 32), 256, 0, stream>>>(qb, kb, vt, ao);
    gemm_k<1><<<dim3(32, 8), 256, 0, stream>>>(ao, wot, bo, nullptr, nullptr,
                                               nullptr, nullptr, nullptr,
                                               (float*)d_out);
}